// Round 1
// baseline (320.152 us; speedup 1.0000x reference)
//
#include <hip/hip_runtime.h>
#include <math.h>

#define B_ 32
#define S_ 1024
#define H_ 512
#define K_ 1024                 // 2*H
#define M_ (B_ * S_)            // 32768

typedef __attribute__((ext_vector_type(8))) short bf16x8;
typedef __attribute__((ext_vector_type(16))) float f32x16;

// Round-half-up split: f = hi + lo.  Residual r = f - fh is EXACT regardless
// of hi's rounding mode, so half-up (1 add) matches RNE accuracy (total A
// error = lo rounding <= 2^-18 rel) at half the VALU cost.
__device__ __forceinline__ void split_bf16(float f, unsigned short& hi, unsigned short& lo) {
    unsigned u = __float_as_uint(f);
    unsigned r = u + 0x8000u;
    hi = (unsigned short)(r >> 16);
    float fh = __uint_as_float(r & 0xffff0000u);
    float res = f - fh;
    lo = (unsigned short)((__float_as_uint(res) + 0x8000u) >> 16);
}

// split 8 floats -> two 16B LDS stores; v_perm packs 2 halves/op.
// ~5 VALU ops/element (was ~12 with RNE + scalar half packing).
__device__ __forceinline__ void split8_store(const float4& x, const float4& y,
                                             unsigned short* hiP, unsigned short* loP) {
    float f[8] = {x.x, x.y, x.z, x.w, y.x, y.y, y.z, y.w};
    unsigned hr[8], lr[8];
    #pragma unroll
    for (int i = 0; i < 8; ++i) {
        unsigned u = __float_as_uint(f[i]);
        unsigned r = u + 0x8000u;
        hr[i] = r;
        float fh = __uint_as_float(r & 0xffff0000u);
        lr[i] = __float_as_uint(f[i] - fh) + 0x8000u;
    }
    uint4 Hv, Lv;
    Hv.x = __builtin_amdgcn_perm(hr[1], hr[0], 0x07060302u);
    Hv.y = __builtin_amdgcn_perm(hr[3], hr[2], 0x07060302u);
    Hv.z = __builtin_amdgcn_perm(hr[5], hr[4], 0x07060302u);
    Hv.w = __builtin_amdgcn_perm(hr[7], hr[6], 0x07060302u);
    Lv.x = __builtin_amdgcn_perm(lr[1], lr[0], 0x07060302u);
    Lv.y = __builtin_amdgcn_perm(lr[3], lr[2], 0x07060302u);
    Lv.z = __builtin_amdgcn_perm(lr[5], lr[4], 0x07060302u);
    Lv.w = __builtin_amdgcn_perm(lr[7], lr[6], 0x07060302u);
    *reinterpret_cast<uint4*>(hiP) = Hv;
    *reinterpret_cast<uint4*>(loP) = Lv;
}

// tanh via HW exp + rcp: (e^2x - 1)/(e^2x + 1).  ~8 ops, |err| ~1e-6.
__device__ __forceinline__ float fast_tanh(float x) {
    float xc = fminf(fmaxf(x, -15.f), 15.f);     // avoid inf/inf
    float t = __expf(2.0f * xc);
    return (t - 1.0f) * __builtin_amdgcn_rcpf(t + 1.0f);
}

// async 16B global -> LDS (lane i lands at lds_base + i*16; lds_base wave-uniform)
__device__ __forceinline__ void async_copy16(const void* g, void* l) {
    __builtin_amdgcn_global_load_lds(
        (const __attribute__((address_space(1))) void*)g,
        (__attribute__((address_space(3))) void*)l, 16, 0, 0);
}

// ---------------------------------------------------------------------------
// Kernel 1: merged prep.
//   blocks [0,256):  hb[b][h] = sum_k hidden[b][k]*W[k][h] + bias[h]
//   blocks [256,768): transpose + bf16-split We (K x 512) -> Wth/Wtl (512 x K)
// ---------------------------------------------------------------------------
__global__ __launch_bounds__(256) void prep_kernel(
    const float* __restrict__ hidden, const float* __restrict__ W,
    const float* __restrict__ bias, float* __restrict__ hb,
    unsigned short* __restrict__ Wh, unsigned short* __restrict__ Wl)
{
    __shared__ float red[4][64];
    __shared__ float t[32][33];
    const int bx = blockIdx.x;
    if (bx < 256) {
        const int tid = threadIdx.x;
        const int h0  = (bx & 7) * 64;
        const int b   = bx >> 3;
        const int h   = h0 + (tid & 63);
        const int ks  = tid >> 6;              // 4 k-slices of 128
        const float* hrow = hidden + b * H_;
        float acc = 0.f;
        #pragma unroll 8
        for (int k = ks * 128; k < ks * 128 + 128; ++k)
            acc = fmaf(hrow[k], W[(size_t)k * H_ + h], acc);
        red[ks][tid & 63] = acc;
        __syncthreads();
        if (tid < 64)
            hb[b * H_ + h0 + tid] = red[0][tid] + red[1][tid] + red[2][tid]
                                  + red[3][tid] + bias[h0 + tid];
    } else {
        const float* We = W + (size_t)H_ * H_;   // rows [H, 3H)
        const int cx = bx - 256;                  // 0..511
        const int k0 = (cx & 31) * 32, n0 = (cx >> 5) * 32;
        const int tx = threadIdx.x & 31, ty = threadIdx.x >> 5;   // ty 0..7
        #pragma unroll
        for (int j = 0; j < 4; ++j) {
            const int k = ty + 8 * j;
            t[k][tx] = We[(size_t)(k0 + k) * H_ + n0 + tx];
        }
        __syncthreads();
        #pragma unroll
        for (int j = 0; j < 4; ++j) {
            const int n = ty + 8 * j;
            unsigned short hi, lo;
            split_bf16(t[tx][n], hi, lo);
            Wh[(size_t)(n0 + n) * K_ + k0 + tx] = hi;
            Wl[(size_t)(n0 + n) * K_ + k0 + tx] = lo;
        }
    }
}

// ---------------------------------------------------------------------------
// Kernel 2: MFMA GEMM, in-loop A split, double-buffered.
//   Changes this round:
//   - 32x32x16 bf16 MFMA (2x2 frags/wave) instead of 16x16x32 (4x4):
//     same LDS layout + XOR quarter-swizzle stays conflict-free (each
//     16-lane group = 16 consecutive rows at fixed segment, as before).
//   - XCD-bijective block swizzle: XCD x = bid%8 owns mt in [32x,32x+32),
//     4 nt-sharers of one mt temporally adjacent on the SAME XCD -> A rows
//     served from XCD-local L2 (was: 4 different XCDs, 2x HBM fetch).
//   - cheap half-up split with v_perm packing (~5 ops/elem, was ~12).
// ---------------------------------------------------------------------------
__global__ __launch_bounds__(256, 2) void gemm_fused(
    const float* __restrict__ EO,             // (M, K) fp32
    const unsigned short* __restrict__ Bth,   // (512, K) bf16 hi
    const unsigned short* __restrict__ Btl,   // (512, K) bf16 lo
    const float* __restrict__ hb, const float* __restrict__ v,
    float* __restrict__ partial)              // (4, M)
{
    __shared__ unsigned short ldsA[2][2][4096];   // [buf][hi|lo][128*32]
    __shared__ unsigned short ldsB[2][2][4096];

    const int tid  = threadIdx.x;
    // XCD-aware decode: bid%8 = XCD; within an XCD, nt fastest then mt.
    const int bid  = blockIdx.x;
    const int j    = bid >> 3;
    const int mt   = (bid & 7) * 32 + (j >> 2);   // 0..255
    const int nt   = j & 3;                        // 0..3
    const int row0 = mt * 128;
    const int col0 = nt * 128;
    const int batch = row0 >> 10;

    const int lane   = tid & 63;
    const int wave   = tid >> 6;
    const int wm     = wave >> 1, wn = wave & 1;
    const int lane32 = lane & 31, khalf = lane >> 5;

    // ---- A staging geometry: seg = tid + 256*s; m = seg>>2; sg = seg&3 ----
    size_t gaA[2];
    int offA[2];
    #pragma unroll
    for (int s = 0; s < 2; ++s) {
        const int seg = tid + 256 * s;
        const int m = seg >> 2, sg = seg & 3;
        gaA[s] = (size_t)(row0 + m) * K_ + sg * 8;
        offA[s] = m * 32 + (sg ^ ((m >> 1) & 3)) * 8;
    }
    // ---- B staging geometry (DMA): issue = 16 rows x 64B; wave w: 2w,2w+1 ----
    size_t gb[2];
    int offB[2];
    #pragma unroll
    for (int jj = 0; jj < 2; ++jj) {
        const int iss = wave * 2 + jj;
        const int r   = iss * 16 + (lane >> 2);
        const int qg  = (lane & 3) ^ ((r >> 1) & 3);
        gb[jj] = (size_t)(col0 + r) * K_ + qg * 8;
        offB[jj] = iss * 512;                 // shorts
    }

    f32x16 acc[2][2];
    #pragma unroll
    for (int fi = 0; fi < 2; ++fi)
        #pragma unroll
        for (int fj = 0; fj < 2; ++fj)
            #pragma unroll
            for (int e = 0; e < 16; ++e)
                acc[fi][fj][e] = 0.f;

    // ---- prologue: stage tile 0 ----
    float4 a0[2], a1[2];
    #pragma unroll
    for (int s = 0; s < 2; ++s) {
        a0[s] = *reinterpret_cast<const float4*>(EO + gaA[s]);
        a1[s] = *reinterpret_cast<const float4*>(EO + gaA[s] + 4);
    }
    #pragma unroll
    for (int jj = 0; jj < 2; ++jj) {
        async_copy16(Bth + gb[jj], &ldsB[0][0][offB[jj]]);
        async_copy16(Btl + gb[jj], &ldsB[0][1][offB[jj]]);
    }
    #pragma unroll
    for (int s = 0; s < 2; ++s)
        split8_store(a0[s], a1[s], &ldsA[0][0][offA[s]], &ldsA[0][1][offA[s]]);

    for (int i = 0; i < 32; ++i) {
        __syncthreads();                      // buf[cur] ready (vmcnt+lgkm drain)
        const int cur = i & 1, nxt = cur ^ 1;
        const int k0n = 32 * (i + 1);
        if (i < 31) {
            // issue next A register loads first (so awaiting them later
            // leaves B DMA still in flight), then B DMA.
            #pragma unroll
            for (int s = 0; s < 2; ++s) {
                a0[s] = *reinterpret_cast<const float4*>(EO + gaA[s] + k0n);
                a1[s] = *reinterpret_cast<const float4*>(EO + gaA[s] + k0n + 4);
            }
            #pragma unroll
            for (int jj = 0; jj < 2; ++jj) {
                async_copy16(Bth + gb[jj] + k0n, &ldsB[nxt][0][offB[jj]]);
                async_copy16(Btl + gb[jj] + k0n, &ldsB[nxt][1][offB[jj]]);
            }
        }

        // ---- fragments: 32x32x16 layout.  A row = l&31; k = (l>>5)*8 + j;
        //      k-seg within BK=32: q = ks*2 + khalf, physical = q ^ swz(row).
        bf16x8 a_h[2][2], a_l[2][2], b_h[2][2], b_l[2][2];
        #pragma unroll
        for (int fi = 0; fi < 2; ++fi) {
            const int m   = wm * 64 + fi * 32 + lane32;
            const int swz = (m >> 1) & 3;
            #pragma unroll
            for (int ks = 0; ks < 2; ++ks) {
                const int sa = (ks * 2 + khalf) ^ swz;
                a_h[fi][ks] = *reinterpret_cast<const bf16x8*>(&ldsA[cur][0][m * 32 + sa * 8]);
                a_l[fi][ks] = *reinterpret_cast<const bf16x8*>(&ldsA[cur][1][m * 32 + sa * 8]);
            }
        }
        #pragma unroll
        for (int fj = 0; fj < 2; ++fj) {
            const int n   = wn * 64 + fj * 32 + lane32;
            const int swz = (n >> 1) & 3;
            #pragma unroll
            for (int ks = 0; ks < 2; ++ks) {
                const int sb = (ks * 2 + khalf) ^ swz;
                b_h[fj][ks] = *reinterpret_cast<const bf16x8*>(&ldsB[cur][0][n * 32 + sb * 8]);
                b_l[fj][ks] = *reinterpret_cast<const bf16x8*>(&ldsB[cur][1][n * 32 + sb * 8]);
            }
        }
        #pragma unroll
        for (int fi = 0; fi < 2; ++fi)
            #pragma unroll
            for (int fj = 0; fj < 2; ++fj)
                #pragma unroll
                for (int ks = 0; ks < 2; ++ks) {
                    acc[fi][fj] = __builtin_amdgcn_mfma_f32_32x32x16_bf16(
                        a_h[fi][ks], b_h[fj][ks], acc[fi][fj], 0, 0, 0);
                    acc[fi][fj] = __builtin_amdgcn_mfma_f32_32x32x16_bf16(
                        a_h[fi][ks], b_l[fj][ks], acc[fi][fj], 0, 0, 0);
                    acc[fi][fj] = __builtin_amdgcn_mfma_f32_32x32x16_bf16(
                        a_l[fi][ks], b_h[fj][ks], acc[fi][fj], 0, 0, 0);
                }

        if (i < 31) {                         // split+stage A(i+1) after MFMAs
            #pragma unroll
            for (int s = 0; s < 2; ++s)
                split8_store(a0[s], a1[s],
                             &ldsA[nxt][0][offA[s]], &ldsA[nxt][1][offA[s]]);
        }
    }

    // ---- epilogue: tanh(acc + hb)*v, reduce over this block's 128 cols ----
    // Last iter read buf 1; red reuses ldsA[0] (disjoint) -> no hazard.
    // 32x32 C layout: col = lane&31, row = (reg&3) + 8*(reg>>2) + 4*(lane>>5).
    const float* hb_row = hb + batch * H_;
    float hbv[2], vv[2];
    #pragma unroll
    for (int fj = 0; fj < 2; ++fj) {
        const int c = col0 + wn * 64 + fj * 32 + lane32;
        hbv[fj] = hb_row[c];
        vv[fj]  = v[c];
    }
    float* red = reinterpret_cast<float*>(&ldsA[0][0][0]);   // 256 floats
    #pragma unroll
    for (int fi = 0; fi < 2; ++fi)
        #pragma unroll
        for (int r = 0; r < 16; ++r) {
            float rs = 0.f;
            #pragma unroll
            for (int fj = 0; fj < 2; ++fj)
                rs = fmaf(fast_tanh(acc[fi][fj][r] + hbv[fj]), vv[fj], rs);
            rs += __shfl_xor(rs, 1, 64);
            rs += __shfl_xor(rs, 2, 64);
            rs += __shfl_xor(rs, 4, 64);
            rs += __shfl_xor(rs, 8, 64);
            rs += __shfl_xor(rs, 16, 64);
            if (lane32 == 0) {
                const int row = wm * 64 + fi * 32 + (r & 3) + 8 * (r >> 2) + 4 * khalf;
                red[row * 2 + wn] = rs;
            }
        }
    __syncthreads();
    if (tid < 128)
        partial[(size_t)nt * M_ + row0 + tid] = red[tid * 2] + red[tid * 2 + 1];
}

// ---------------------------------------------------------------------------
// Kernel 3: per-batch softmax over S=1024 (sum of 4 partials)
// ---------------------------------------------------------------------------
__global__ __launch_bounds__(256) void softmax_kernel(
    const float* __restrict__ partial, float* __restrict__ out)
{
    const int b = blockIdx.x;
    const int tid = threadIdx.x;
    float val[4];
    float lmax = -3.0e38f;
    #pragma unroll
    for (int q = 0; q < 4; ++q) {
        const int idx = b * S_ + tid + 256 * q;
        float sum = partial[idx] + partial[M_ + idx] + partial[2 * M_ + idx] +
                    partial[3 * M_ + idx];
        val[q] = sum;
        lmax = fmaxf(lmax, sum);
    }
    #pragma unroll
    for (int off = 32; off > 0; off >>= 1)
        lmax = fmaxf(lmax, __shfl_down(lmax, off, 64));
    __shared__ float wmax[4];
    if ((tid & 63) == 0) wmax[tid >> 6] = lmax;
    __syncthreads();
    const float gmax = fmaxf(fmaxf(wmax[0], wmax[1]), fmaxf(wmax[2], wmax[3]));
    float lsum = 0.0f;
    #pragma unroll
    for (int q = 0; q < 4; ++q) {
        val[q] = expf(val[q] - gmax);
        lsum += val[q];
    }
    #pragma unroll
    for (int off = 32; off > 0; off >>= 1)
        lsum += __shfl_down(lsum, off, 64);
    __shared__ float wsum[4];
    if ((tid & 63) == 0) wsum[tid >> 6] = lsum;
    __syncthreads();
    const float inv = 1.0f / (wsum[0] + wsum[1] + wsum[2] + wsum[3]);
    #pragma unroll
    for (int q = 0; q < 4; ++q)
        out[b * S_ + tid + 256 * q] = val[q] * inv;
}

// ---------------------------------------------------------------------------
extern "C" void kernel_launch(void* const* d_in, const int* in_sizes, int n_in,
                              void* d_out, int out_size, void* d_ws, size_t ws_size,
                              hipStream_t stream) {
    const float* hidden = (const float*)d_in[0];
    const float* EO     = (const float*)d_in[1];
    const float* W      = (const float*)d_in[2];
    const float* bias   = (const float*)d_in[3];
    const float* v      = (const float*)d_in[4];
    float* out          = (float*)d_out;

    float* hb      = (float*)d_ws;                       // 16384 floats
    float* partial = hb + B_ * H_;                       // 131072 floats
    unsigned short* Wth = (unsigned short*)(partial + 4 * M_);
    unsigned short* Wtl = Wth + (size_t)H_ * K_;

    prep_kernel<<<768, 256, 0, stream>>>(hidden, W, bias, hb, Wth, Wtl);
    gemm_fused<<<dim3(1024), 256, 0, stream>>>(EO, Wth, Wtl, hb, v, partial);
    softmax_kernel<<<B_, 256, 0, stream>>>(partial, out);
}